// Round 1
// baseline (89.925 us; speedup 1.0000x reference)
//
#include <hip/hip_runtime.h>
#include <math.h>

#define SRATE 48000
#define NN    480000
#define MAXD  50
#define CHUNK 32
#define TPB   256
#define NBLK  59                 // ceil(480000 / (32*256))
#define NTHR  (NBLK * TPB)       // 15104 threads total in scan kernels

__device__ __forceinline__ float clampf(float v, float lo, float hi) {
    return fminf(fmaxf(v, lo), hi);
}

struct Params { float al, bl, ah, bh, feedback, gain; int dl, nd; };

__device__ __forceinline__ Params load_params(const float* __restrict__ p) {
    Params q;
    float freq  = clampf(p[0], 20.0f, (float)(SRATE / 2));
    q.feedback  = clampf(p[1], 0.0f, 0.99f);
    float alow  = clampf(p[2], 1e-7f, 0.99f);
    float ahigh = clampf(p[3], 1e-7f, 0.99f);
    q.gain      = fmaxf(p[4], 1e-7f);
    float dlf   = clampf(floorf((float)SRATE / freq), 1.0f, (float)(NN / 2));
    q.dl = (int)dlf;
    q.nd = min(NN / q.dl, MAXD);
    q.al = alow;  q.bl = 1.0f - alow;
    q.ah = ahigh; q.bh = 1.0f - ahigh;
    return q;
}

// Phase 1: per-thread chunk scan from zero state -> affine (Y, D) per filter,
// block-level LDS inclusive scan of affines, store per-thread exclusive
// prefixes and per-block aggregates.
__global__ __launch_bounds__(TPB) void scan_phase1(
    const float* __restrict__ x, const float* __restrict__ p,
    float* __restrict__ thrYl, float* __restrict__ thrDl,
    float* __restrict__ thrYh, float* __restrict__ thrDh,
    float* __restrict__ blkYl, float* __restrict__ blkDl,
    float* __restrict__ blkYh, float* __restrict__ blkDh)
{
    Params q = load_params(p);
    int tid = threadIdx.x;
    int t = blockIdx.x * TPB + tid;
    int start = t * CHUNK;
    int len = NN - start; len = (len < 0) ? 0 : ((len > CHUNK) ? CHUNK : len);

    float yl = 0.f, yh = 0.f, dl = 1.f, dh = 1.f;
    for (int j = 0; j < len; ++j) {
        float xv = x[start + j];
        yl = fmaf(q.bl, yl, q.al * xv);
        yh = fmaf(q.bh, yh, q.ah * xv);
        dl *= q.bl; dh *= q.bh;
    }

    __shared__ float sYl[TPB], sDl[TPB], sYh[TPB], sDh[TPB];
    sYl[tid] = yl; sDl[tid] = dl; sYh[tid] = yh; sDh[tid] = dh;
    __syncthreads();
    // Hillis-Steele inclusive scan; op(earlier, later) = later ∘ earlier
    for (int off = 1; off < TPB; off <<= 1) {
        float cYl = sYl[tid], cDl = sDl[tid], cYh = sYh[tid], cDh = sDh[tid];
        float pYl = 0.f, pDl = 1.f, pYh = 0.f, pDh = 1.f;
        bool has = (tid >= off);
        if (has) { pYl = sYl[tid - off]; pDl = sDl[tid - off];
                   pYh = sYh[tid - off]; pDh = sDh[tid - off]; }
        __syncthreads();
        if (has) {
            sYl[tid] = fmaf(cDl, pYl, cYl); sDl[tid] = cDl * pDl;
            sYh[tid] = fmaf(cDh, pYh, cYh); sDh[tid] = cDh * pDh;
        }
        __syncthreads();
    }

    float eYl = 0.f, eDl = 1.f, eYh = 0.f, eDh = 1.f;
    if (tid > 0) { eYl = sYl[tid-1]; eDl = sDl[tid-1];
                   eYh = sYh[tid-1]; eDh = sDh[tid-1]; }
    thrYl[t] = eYl; thrDl[t] = eDl; thrYh[t] = eYh; thrDh[t] = eDh;

    if (tid == TPB - 1) {
        blkYl[blockIdx.x] = sYl[tid]; blkDl[blockIdx.x] = sDl[tid];
        blkYh[blockIdx.x] = sYh[tid]; blkDh[blockIdx.x] = sDh[tid];
    }
}

// Phase 2: each block redundantly scans the 59 block aggregates (wave 0,
// shuffles) to get its scalar carry-in; threads seed their chunk recurrence
// with the exact entering state and write filtered = y_high - y_low.
__global__ __launch_bounds__(TPB) void scan_phase2(
    const float* __restrict__ x, const float* __restrict__ p,
    const float* __restrict__ thrYl, const float* __restrict__ thrDl,
    const float* __restrict__ thrYh, const float* __restrict__ thrDh,
    const float* __restrict__ blkYl, const float* __restrict__ blkDl,
    const float* __restrict__ blkYh, const float* __restrict__ blkDh,
    float* __restrict__ filtered)
{
    Params q = load_params(p);
    __shared__ float sCl, sCh;
    int tid = threadIdx.x;

    if (tid < 64) {                     // wave 0 only (uniform branch)
        int l = tid;
        float Yl = (l < NBLK) ? blkYl[l] : 0.f;
        float Dl = (l < NBLK) ? blkDl[l] : 1.f;
        float Yh = (l < NBLK) ? blkYh[l] : 0.f;
        float Dh = (l < NBLK) ? blkDh[l] : 1.f;
        for (int off = 1; off < 64; off <<= 1) {
            float pYl = __shfl_up(Yl, off);
            float pDl = __shfl_up(Dl, off);
            float pYh = __shfl_up(Yh, off);
            float pDh = __shfl_up(Dh, off);
            if (l >= off) {
                Yl = fmaf(Dl, pYl, Yl); Dl *= pDl;
                Yh = fmaf(Dh, pYh, Yh); Dh *= pDh;
            }
        }
        int b = blockIdx.x;
        int src = (b == 0) ? 0 : (b - 1);
        float selYl = __shfl(Yl, src);  // inclusive prefix of block b-1
        float selYh = __shfl(Yh, src);
        if (l == 0) {
            sCl = (b == 0) ? 0.f : selYl;
            sCh = (b == 0) ? 0.f : selYh;
        }
    }
    __syncthreads();

    int t = blockIdx.x * TPB + tid;
    float yl = fmaf(thrDl[t], sCl, thrYl[t]);   // exact entering state
    float yh = fmaf(thrDh[t], sCh, thrYh[t]);
    int start = t * CHUNK;
    int len = NN - start; len = (len < 0) ? 0 : ((len > CHUNK) ? CHUNK : len);
    for (int j = 0; j < len; ++j) {
        float xv = x[start + j];
        yl = fmaf(q.bl, yl, q.al * xv);
        yh = fmaf(q.bh, yh, q.ah * xv);
        filtered[start + j] = yh - yl;
    }
}

// Phase 3: tap accumulation + tanh. filtered[n-s] reads are coalesced per tap
// and the 1.92 MB array is L2-resident.
__global__ __launch_bounds__(TPB) void taps_kernel(
    const float* __restrict__ input, const float* __restrict__ p,
    const float* __restrict__ filtered, float* __restrict__ out)
{
    int n = blockIdx.x * TPB + threadIdx.x;
    if (n >= NN) return;
    Params q = load_params(p);
    float acc = input[n];
    int s = q.dl;
    float w = q.feedback;
    for (int i = 1; i < q.nd; ++i) {
        if (s > n) break;               // shifts are monotone increasing
        acc = fmaf(w, filtered[n - s], acc);
        s += q.dl;
        w *= q.feedback;
    }
    out[n] = tanhf(acc * q.gain);
}

extern "C" void kernel_launch(void* const* d_in, const int* in_sizes, int n_in,
                              void* d_out, int out_size, void* d_ws, size_t ws_size,
                              hipStream_t stream)
{
    const float* input  = (const float*)d_in[0];
    const float* params = (const float*)d_in[1];
    const float* dbuf   = (const float*)d_in[2];
    float* out = (float*)d_out;

    float* ws       = (float*)d_ws;
    float* filtered = ws;               // NN floats
    float* thrYl = ws + NN;             // NTHR each
    float* thrDl = thrYl + NTHR;
    float* thrYh = thrDl + NTHR;
    float* thrDh = thrYh + NTHR;
    float* blkYl = thrDh + NTHR;        // NBLK each
    float* blkDl = blkYl + NBLK;
    float* blkYh = blkDl + NBLK;
    float* blkDh = blkYh + NBLK;

    scan_phase1<<<NBLK, TPB, 0, stream>>>(dbuf, params,
        thrYl, thrDl, thrYh, thrDh, blkYl, blkDl, blkYh, blkDh);
    scan_phase2<<<NBLK, TPB, 0, stream>>>(dbuf, params,
        thrYl, thrDl, thrYh, thrDh, blkYl, blkDl, blkYh, blkDh, filtered);
    taps_kernel<<<(NN + TPB - 1) / TPB, TPB, 0, stream>>>(input, params, filtered, out);
}

// Round 2
// 76.696 us; speedup vs baseline: 1.1725x; 1.1725x over previous
//
#include <hip/hip_runtime.h>
#include <math.h>

#define SRATE 48000
#define NN    480000
#define MAXD  50
#define TPB   256
#define NV4   (NN / 4)                     // 120000 float4 segments
#define NBLKS ((NV4 + TPB - 1) / TPB)      // 469 scan blocks
#define NTAPB (NN / TPB)                   // 1875 taps blocks

__device__ __forceinline__ float clampf(float v, float lo, float hi) {
    return fminf(fmaxf(v, lo), hi);
}

struct Params { float al, bl, ah, bh, feedback, gain; int dl, nd; };

__device__ __forceinline__ Params load_params(const float* __restrict__ p) {
    Params q;
    float freq  = clampf(p[0], 20.0f, (float)(SRATE / 2));
    q.feedback  = clampf(p[1], 0.0f, 0.99f);
    float alow  = clampf(p[2], 1e-7f, 0.99f);
    float ahigh = clampf(p[3], 1e-7f, 0.99f);
    q.gain      = fmaxf(p[4], 1e-7f);
    float dlf   = clampf(floorf((float)SRATE / freq), 1.0f, (float)(NN / 2));
    q.dl = (int)dlf;
    q.nd = min(NN / q.dl, MAXD);
    q.al = alow;  q.bl = 1.0f - alow;
    q.ah = ahigh; q.bh = 1.0f - ahigh;
    return q;
}

// Thread-local affine over a float4 segment: state_out = Y + D*state_in.
__device__ __forceinline__ void seg_affine(const float4& v, float a, float b,
                                           float& Y, float& D) {
    float t = v.x;
    t = fmaf(t, b, v.y);
    t = fmaf(t, b, v.z);
    t = fmaf(t, b, v.w);
    Y = a * t;
    float b2 = b * b;
    D = b2 * b2;
}

// Wave-level inclusive scan of affine pairs (composition: later ∘ earlier).
__device__ __forceinline__ void wave_scan(int lane, float& Yl, float& Dl,
                                          float& Yh, float& Dh) {
    for (int off = 1; off < 64; off <<= 1) {
        float pYl = __shfl_up(Yl, off), pDl = __shfl_up(Dl, off);
        float pYh = __shfl_up(Yh, off), pDh = __shfl_up(Dh, off);
        if (lane >= off) {
            Yl = fmaf(Dl, pYl, Yl); Dl *= pDl;
            Yh = fmaf(Dh, pYh, Yh); Dh *= pDh;
        }
    }
}

// Kernel A: per-block affine aggregate (both filters) -> blkAgg[b] = (Yl,Dl,Yh,Dh)
__global__ __launch_bounds__(TPB) void scan_agg(
    const float* __restrict__ x, const float* __restrict__ p,
    float4* __restrict__ blkAgg)
{
    Params q = load_params(p);
    int tid = threadIdx.x;
    int t = blockIdx.x * TPB + tid;
    float Yl = 0.f, Dl = 1.f, Yh = 0.f, Dh = 1.f;
    if (t < NV4) {
        float4 v = ((const float4*)x)[t];
        seg_affine(v, q.al, q.bl, Yl, Dl);
        seg_affine(v, q.ah, q.bh, Yh, Dh);
    }
    int lane = tid & 63;
    wave_scan(lane, Yl, Dl, Yh, Dh);

    __shared__ float wYl[4], wDl[4], wYh[4], wDh[4];
    int w = tid >> 6;
    if (lane == 63) { wYl[w] = Yl; wDl[w] = Dl; wYh[w] = Yh; wDh[w] = Dh; }
    __syncthreads();
    if (tid == TPB - 1) {                 // lane 63 of wave 3 holds its inclusive
        float cYl = 0.f, cDl = 1.f, cYh = 0.f, cDh = 1.f;
        for (int j = 0; j < 3; ++j) {     // compose waves 0..2 in order
            cYl = fmaf(wDl[j], cYl, wYl[j]); cDl *= wDl[j];
            cYh = fmaf(wDh[j], cYh, wYh[j]); cDh *= wDh[j];
        }
        float AYl = fmaf(Dl, cYl, Yl), ADl = Dl * cDl;
        float AYh = fmaf(Dh, cYh, Yh), ADh = Dh * cDh;
        blkAgg[blockIdx.x] = make_float4(AYl, ADl, AYh, ADh);
    }
}

// Kernel B: redundant block-carry scan + local re-scan + apply, write filtered.
__global__ __launch_bounds__(TPB) void scan_apply(
    const float* __restrict__ x, const float* __restrict__ p,
    const float4* __restrict__ blkAgg,
    float* __restrict__ filtered)
{
    Params q = load_params(p);
    int tid = threadIdx.x;
    int lane = tid & 63;
    int w = tid >> 6;
    int t = blockIdx.x * TPB + tid;
    bool valid = (t < NV4);

    float4 v = make_float4(0.f, 0.f, 0.f, 0.f);
    float Yl = 0.f, Dl = 1.f, Yh = 0.f, Dh = 1.f;
    if (valid) {
        v = ((const float4*)x)[t];
        seg_affine(v, q.al, q.bl, Yl, Dl);
        seg_affine(v, q.ah, q.bh, Yh, Dh);
    }
    wave_scan(lane, Yl, Dl, Yh, Dh);

    __shared__ float wYl[4], wDl[4], wYh[4], wDh[4];
    if (lane == 63) { wYl[w] = Yl; wDl[w] = Dl; wYh[w] = Yh; wDh[w] = Dh; }

    // ---- block-carry: scan 469 aggregates (pair-compose + Hillis-Steele) ----
    __shared__ float sYl[TPB], sDl[TPB], sYh[TPB], sDh[TPB];
    {
        int i2 = 2 * tid;
        float4 a0 = (i2     < NBLKS) ? blkAgg[i2]     : make_float4(0.f, 1.f, 0.f, 1.f);
        float4 a1 = (i2 + 1 < NBLKS) ? blkAgg[i2 + 1] : make_float4(0.f, 1.f, 0.f, 1.f);
        sYl[tid] = fmaf(a1.y, a0.x, a1.x); sDl[tid] = a1.y * a0.y;
        sYh[tid] = fmaf(a1.w, a0.z, a1.z); sDh[tid] = a1.w * a0.w;
    }
    __syncthreads();
    for (int off = 1; off < TPB; off <<= 1) {
        float cyl = sYl[tid], cdl = sDl[tid], cyh = sYh[tid], cdh = sDh[tid];
        float pyl = 0.f, pdl = 1.f, pyh = 0.f, pdh = 1.f;
        bool has = (tid >= off);
        if (has) { pyl = sYl[tid-off]; pdl = sDl[tid-off];
                   pyh = sYh[tid-off]; pdh = sDh[tid-off]; }
        __syncthreads();
        if (has) {
            sYl[tid] = fmaf(cdl, pyl, cyl); sDl[tid] = cdl * pdl;
            sYh[tid] = fmaf(cdh, pyh, cyh); sDh[tid] = cdh * pdh;
        }
        __syncthreads();
    }
    __shared__ float GYl_s, GYh_s;
    if (tid == 0) {
        int b = blockIdx.x;
        int qq = b >> 1;
        float GYl = 0.f, GDl = 1.f, GYh = 0.f, GDh = 1.f;
        if (qq > 0) { GYl = sYl[qq-1]; GDl = sDl[qq-1];
                      GYh = sYh[qq-1]; GDh = sDh[qq-1]; }
        if (b & 1) {                      // also fold in block 2q
            float4 am = blkAgg[2 * qq];
            GYl = fmaf(am.y, GYl, am.x); GDl = am.y * GDl;
            GYh = fmaf(am.w, GYh, am.z); GDh = am.w * GDh;
        }
        (void)GDl; (void)GDh;             // initial state is 0: only Y matters
        GYl_s = GYl; GYh_s = GYh;
    }
    __syncthreads();

    // ---- per-thread entering state = laneExcl ∘ waveCarry applied to GY ----
    float eYl = __shfl_up(Yl, 1), eDl = __shfl_up(Dl, 1);
    float eYh = __shfl_up(Yh, 1), eDh = __shfl_up(Dh, 1);
    if (lane == 0) { eYl = 0.f; eDl = 1.f; eYh = 0.f; eDh = 1.f; }
    float cYl = 0.f, cDl = 1.f, cYh = 0.f, cDh = 1.f;
    for (int j = 0; j < 3; ++j) {
        if (j < w) {
            cYl = fmaf(wDl[j], cYl, wYl[j]); cDl *= wDl[j];
            cYh = fmaf(wDh[j], cYh, wYh[j]); cDh *= wDh[j];
        }
    }
    // block-local exclusive prefix E = laneExcl ∘ waveCarry
    float BYl = fmaf(eDl, cYl, eYl), BDl = eDl * cDl;
    float BYh = fmaf(eDh, cYh, eYh), BDh = eDh * cDh;
    // state entering this thread's 4 elements
    float yl = fmaf(BDl, GYl_s, BYl);
    float yh = fmaf(BDh, GYh_s, BYh);

    if (valid) {
        float4 o;
        yl = fmaf(q.bl, yl, q.al * v.x); yh = fmaf(q.bh, yh, q.ah * v.x); o.x = yh - yl;
        yl = fmaf(q.bl, yl, q.al * v.y); yh = fmaf(q.bh, yh, q.ah * v.y); o.y = yh - yl;
        yl = fmaf(q.bl, yl, q.al * v.z); yh = fmaf(q.bh, yh, q.ah * v.z); o.z = yh - yl;
        yl = fmaf(q.bl, yl, q.al * v.w); yh = fmaf(q.bh, yh, q.ah * v.w); o.w = yh - yl;
        ((float4*)filtered)[t] = o;
    }
}

// Kernel C: tap accumulation + tanh. filtered reads are coalesced per tap and
// L2/L3-resident (1.92 MB).
__global__ __launch_bounds__(TPB) void taps_kernel(
    const float* __restrict__ input, const float* __restrict__ p,
    const float* __restrict__ filtered, float* __restrict__ out)
{
    int n = blockIdx.x * TPB + threadIdx.x;
    if (n >= NN) return;
    Params q = load_params(p);
    float acc = input[n];
    int m = min(q.nd - 1, n / q.dl);      // number of active taps for this n
    int s = q.dl;
    float w = q.feedback;
    for (int i = 1; i <= m; ++i) {
        acc = fmaf(w, filtered[n - s], acc);
        s += q.dl;
        w *= q.feedback;
    }
    out[n] = tanhf(acc * q.gain);
}

extern "C" void kernel_launch(void* const* d_in, const int* in_sizes, int n_in,
                              void* d_out, int out_size, void* d_ws, size_t ws_size,
                              hipStream_t stream)
{
    const float* input  = (const float*)d_in[0];
    const float* params = (const float*)d_in[1];
    const float* dbuf   = (const float*)d_in[2];
    float* out = (float*)d_out;

    float* ws       = (float*)d_ws;
    float* filtered = ws;                         // NN floats (16B-aligned)
    float4* blkAgg  = (float4*)(ws + NN);         // NBLKS float4s

    scan_agg  <<<NBLKS, TPB, 0, stream>>>(dbuf, params, blkAgg);
    scan_apply<<<NBLKS, TPB, 0, stream>>>(dbuf, params, blkAgg, filtered);
    taps_kernel<<<NTAPB, TPB, 0, stream>>>(input, params, filtered, out);
}